// Round 5
// baseline (352.186 us; speedup 1.0000x reference)
//
#include <hip/hip_runtime.h>

// LSTM encoder B=1024,S=64,H=256 — v5: two-group batch pipelining.
// 32 clusters x 8 WGs x 512 threads (cooperative). Cluster owns 32 batches,
// split into groups A/B of 16; phases alternate A,B so one group's h-exchange
// (MALL RTT) hides under the other group's MFMA+cell. Weights register-
// resident (wf[16], pinned). Per-WAVE flags set after inline s_waitcnt
// vmcnt(0); wave-parallel poll (64 flags, one load/lane + __all); gather
// issued one phase early into registers.

typedef __attribute__((ext_vector_type(8))) short short8;
typedef __attribute__((ext_vector_type(4))) float f32x4;
typedef unsigned long long u64;
typedef unsigned int u32;
typedef unsigned short u16;

#define B_ 1024
#define S_ 64
#define H_ 256
#define G_ 1024
#define KW 512
#define OUTN (B_*S_*H_)
#define APITCH 520      // A-tile pitch (u16)
#define GPITCH 132      // gates tile pitch (f32)
#define NCL 32
#define CWG 8

__device__ __forceinline__ u16 f2bf(float f){
    u32 u = __builtin_bit_cast(u32, f);
    u = (u + 0x7fffu + ((u >> 16) & 1u)) >> 16;   // RNE
    return (u16)u;
}
__device__ __forceinline__ float sigm(float v){ return 1.0f/(1.0f + __expf(-v)); }
__device__ __forceinline__ float tanh_(float v){ return 2.0f/(1.0f + __expf(-2.0f*v)) - 1.0f; }
__device__ __forceinline__ short8 pack8(const f32x4& a, const f32x4& b){
    short8 r;
    r[0]=(short)f2bf(a[0]); r[1]=(short)f2bf(a[1]);
    r[2]=(short)f2bf(a[2]); r[3]=(short)f2bf(a[3]);
    r[4]=(short)f2bf(b[0]); r[5]=(short)f2bf(b[1]);
    r[6]=(short)f2bf(b[2]); r[7]=(short)f2bf(b[3]);
    return r;
}

__global__ __launch_bounds__(256) void prep_kernel(const float* __restrict__ Wih,
        const float* __restrict__ Whh, const float* __restrict__ bih,
        const float* __restrict__ bhh, const float* __restrict__ h0,
        u16* __restrict__ Wc, float* __restrict__ bias,
        u16* __restrict__ hbuf, u32* __restrict__ flg){
    int idx = blockIdx.x*256 + threadIdx.x;
    if (idx < G_*KW){
        int g = idx >> 9, k = idx & 511;
        float v = (k < H_) ? Wih[g*H_ + k] : Whh[g*H_ + (k - H_)];
        Wc[idx] = f2bf(v);
    }
    if (idx < B_*H_) hbuf[idx] = f2bf(h0[idx]);   // h(0) -> buffer 0
    if (idx < G_) bias[idx] = bih[idx] + bhh[idx];
    if (idx < 2*NCL*64) flg[idx] = 0u;
}

__global__ __launch_bounds__(512, 2) void lstm_kernel(
        const float* __restrict__ x, const float* __restrict__ c0,
        const u16* __restrict__ Wc, const float* __restrict__ bias,
        u16* hbuf, u32* flg, float* __restrict__ out){
    __shared__ u16  At0[16*APITCH], At1[16*APITCH];   // 16,640 B each
    __shared__ float Gt0[16*GPITCH], Gt1[16*GPITCH];  //  8,448 B each

    const int tid  = threadIdx.x;
    const int lane = tid & 63;
    const int w    = tid >> 6;
    const int wn   = w >> 1, tn = w & 1;
    const int nl   = lane & 15, kg = lane >> 4;
    const int bid  = blockIdx.x;
    const int cl   = bid & (NCL-1);
    const int j    = bid >> 5;        // wg-in-cluster 0..7
    const int b0   = cl * 32;
    const int d0   = j * 32;
    const int myidx= j*8 + w;         // this wave's flag slot (0..63)

    // ---- persistent W: wave holds 16 gate rows ----
    const int grow_idx = wn*256 + d0 + tn*16 + nl;
    short8 wf[16];
    {
        const u16* wp = Wc + (size_t)grow_idx*KW + kg*8;
        #pragma unroll
        for (int kf = 0; kf < 16; ++kf) wf[kf] = *(const short8*)(wp + kf*32);
    }
    #pragma unroll
    for (int kf = 0; kf < 16; ++kf) asm volatile("" : "+v"(wf[kf]));  // pin
    const float bias_l = bias[grow_idx];

    const int bb  = tid >> 5;    // 0..15 batch within group
    const int dd  = tid & 31;    // cell dim within WG slice
    const int blk = tid & 31;    // 8-dim staging block

    float cr0 = c0[(size_t)(b0 + bb)*H_ + d0 + dd];
    float cr1 = c0[(size_t)(b0 + 16 + bb)*H_ + d0 + dd];

    f32x4 xr0a, xr0b, xr1a, xr1b;     // x prefetch regs per group
    u64 g0r = 0, g1r = 0;             // gather regs (next phase's h)

    // ---- prologue: stage x(0)+h(0) both groups; prefetch x(1) ----
    {
        int bg0 = b0 + bb, bg1 = b0 + 16 + bb;
        const float* p0 = x + (size_t)bg0*S_*H_ + blk*8;
        const float* p1 = x + (size_t)bg1*S_*H_ + blk*8;
        f32x4 a0 = *(const f32x4*)p0, b0v = *(const f32x4*)(p0+4);
        f32x4 a1 = *(const f32x4*)p1, b1v = *(const f32x4*)(p1+4);
        *(short8*)(At0 + bb*APITCH + blk*8) = pack8(a0, b0v);
        *(short8*)(At1 + bb*APITCH + blk*8) = pack8(a1, b1v);
        const u64* h0p = (const u64*)(hbuf + (size_t)bg0*H_ + blk*8);
        const u64* h1p = (const u64*)(hbuf + (size_t)bg1*H_ + blk*8);
        u64 q0 = h0p[0], q1 = h0p[1], q2 = h1p[0], q3 = h1p[1];
        *(u64*)(At0 + bb*APITCH + H_ + blk*8)     = q0;
        *(u64*)(At0 + bb*APITCH + H_ + blk*8 + 4) = q1;
        *(u64*)(At1 + bb*APITCH + H_ + blk*8)     = q2;
        *(u64*)(At1 + bb*APITCH + H_ + blk*8 + 4) = q3;
        xr0a = *(const f32x4*)(p0 + H_); xr0b = *(const f32x4*)(p0 + H_ + 4);
        xr1a = *(const f32x4*)(p1 + H_); xr1b = *(const f32x4*)(p1 + H_ + 4);
    }
    __syncthreads();

#define PHASE(GI, SV)  do {                                                    \
    const int s_  = (SV);                                                      \
    const int s2_ = 2*s_ + (GI);                                               \
    u16*   Atg = (GI) ? At1 : At0;                                             \
    float* Gtg = (GI) ? Gt1 : Gt0;                                             \
    float& crg = (GI) ? cr1 : cr0;                                             \
    f32x4& xga = (GI) ? xr1a : xr0a;                                           \
    f32x4& xgb = (GI) ? xr1b : xr0b;                                           \
    const int bg = b0 + (GI)*16 + bb;                                          \
    /* (A) write prev-phase gather regs -> At h-cols (skip own slice) */       \
    if (s2_ >= 2 && (blk >> 2) != j){                                          \
        *(u64*)(Atg + bb*APITCH + H_ + blk*8)     = g0r;                       \
        *(u64*)(Atg + bb*APITCH + H_ + blk*8 + 4) = g1r;                       \
    }                                                                          \
    __syncthreads();                                                           \
    /* (C) MFMA K=512, 2 dep-chains */                                         \
    f32x4 acc_e = (f32x4){bias_l, bias_l, bias_l, bias_l};                     \
    f32x4 acc_o = (f32x4){0.f, 0.f, 0.f, 0.f};                                 \
    {                                                                          \
        const u16* ar = Atg + nl*APITCH + kg*8;                                \
        _Pragma("unroll")                                                      \
        for (int kf = 0; kf < 16; kf += 2){                                    \
            short8 a0 = *(const short8*)(ar + kf*32);                          \
            short8 a1 = *(const short8*)(ar + (kf+1)*32);                      \
            acc_e = __builtin_amdgcn_mfma_f32_16x16x32_bf16(a0, wf[kf],   acc_e, 0,0,0); \
            acc_o = __builtin_amdgcn_mfma_f32_16x16x32_bf16(a1, wf[kf+1], acc_o, 0,0,0); \
        }                                                                      \
    }                                                                          \
    {                                                                          \
        const int colc = wn*32 + tn*16 + nl;                                   \
        _Pragma("unroll")                                                      \
        for (int jj = 0; jj < 4; ++jj)                                         \
            Gtg[(kg*4 + jj)*GPITCH + colc] = acc_e[jj] + acc_o[jj];            \
    }                                                                          \
    __syncthreads();                                                           \
    /* (E) cell: 1 dim/thread */                                               \
    const float* grp = Gtg + bb*GPITCH + dd;                                   \
    float iv = grp[0], fv = grp[32], gv = grp[64], ov = grp[96];               \
    float cn = sigm(fv)*crg + sigm(iv)*tanh_(gv);                              \
    float hn = sigm(ov)*tanh_(cn);                                             \
    crg = cn;                                                                  \
    u32 hb = (u32)f2bf(hn);                                                    \
    u32 nb = (u32)__shfl_xor((int)hb, 1);                                      \
    float hn2 = __shfl_xor(hn, 1);                                             \
    u32 hpk = hb | (nb << 16);                                                 \
    if (s_ < S_-1 && !(dd & 1)){                                               \
        u16* hnext = hbuf + (size_t)((s_+1)&1)*(B_*H_);                        \
        __hip_atomic_store((u32*)(hnext + (size_t)bg*H_ + d0 + dd), hpk,       \
                           __ATOMIC_RELAXED, __HIP_MEMORY_SCOPE_AGENT);        \
        *(u32*)(Atg + bb*APITCH + H_ + d0 + dd) = hpk;                         \
    }                                                                          \
    /* (G/H) poll other group's flags; issue its gather loads */               \
    if (s2_ < 2*S_-1){                                                         \
        const u32 tgt = (u32)((s2_+1) >> 1);                                   \
        const u32* fp = flg + ((GI)^1)*(NCL*64) + cl*64;                       \
        if (tgt > 0){                                                          \
            int guard = 0;                                                     \
            for(;;){                                                           \
                u32 f = (lane == myidx) ? 0xFFFFFFFFu :                        \
                    __hip_atomic_load(fp + lane, __ATOMIC_RELAXED,             \
                                      __HIP_MEMORY_SCOPE_AGENT);               \
                if (__all((int)(f >= tgt))) break;                             \
                if (++guard > (1<<18)) break;   /* fail loud, no hang */       \
            }                                                                  \
        }                                                                      \
        if ((blk >> 2) != j){                                                  \
            const u64* hs = (const u64*)(hbuf + (size_t)(tgt&1)*(B_*H_)        \
                          + (size_t)(b0 + (((GI)^1))*16 + bb)*H_ + blk*8);     \
            g0r = __hip_atomic_load(hs,   __ATOMIC_RELAXED, __HIP_MEMORY_SCOPE_AGENT); \
            g1r = __hip_atomic_load(hs+1, __ATOMIC_RELAXED, __HIP_MEMORY_SCOPE_AGENT); \
        }                                                                      \
    }                                                                          \
    /* (F) per-wave drain + flag */                                            \
    if (s_ < S_-1){                                                            \
        asm volatile("s_waitcnt vmcnt(0)" ::: "memory");                       \
        if (lane == 0)                                                         \
            __hip_atomic_store(flg + (GI)*(NCL*64) + cl*64 + myidx,            \
                (u32)(s_+1), __ATOMIC_RELAXED, __HIP_MEMORY_SCOPE_AGENT);      \
    }                                                                          \
    /* (I) out stores + x restage(s+1) + x prefetch(s+2) */                    \
    {                                                                          \
        size_t o = ((size_t)bg*S_ + s_)*H_ + d0 + dd;                          \
        if (!(dd & 1)){                                                        \
            float2 hv; hv.x = hn; hv.y = hn2;                                  \
            *(float2*)(out + o) = hv;                                          \
            *(float2*)(out + OUTN + o) = hv;                                   \
        }                                                                      \
        if (s_ + 1 < S_)                                                       \
            *(short8*)(Atg + bb*APITCH + blk*8) = pack8(xga, xgb);             \
        if (s_ + 2 < S_){                                                      \
            const float* xq = x + ((size_t)bg*S_ + (s_+2))*H_ + blk*8;         \
            xga = *(const f32x4*)xq;                                           \
            xgb = *(const f32x4*)(xq+4);                                       \
        }                                                                      \
    }                                                                          \
} while(0)

    #pragma unroll 1
    for (int s = 0; s < S_; ++s){
        PHASE(0, s);
        PHASE(1, s);
    }
#undef PHASE
}

extern "C" void kernel_launch(void* const* d_in, const int* in_sizes, int n_in,
                              void* d_out, int out_size, void* d_ws, size_t ws_size,
                              hipStream_t stream){
    const float* x   = (const float*)d_in[0];
    const float* h0  = (const float*)d_in[1];
    const float* c0  = (const float*)d_in[2];
    const float* Wih = (const float*)d_in[3];
    const float* Whh = (const float*)d_in[4];
    const float* bih = (const float*)d_in[5];
    const float* bhh = (const float*)d_in[6];

    u16*   Wc   = (u16*)d_ws;                          // 1 MB @ 0
    float* bias = (float*)((char*)d_ws + 0x100000);    // 4 KB
    u32*   flg  = (u32*)((char*)d_ws + 0x101000);      // 16 KB (2 x 32 x 64)
    u16*   hbuf = (u16*)((char*)d_ws + 0x108000);      // 1 MB (double buffer)
    float* outp = (float*)d_out;

    prep_kernel<<<(G_*KW + 255)/256, 256, 0, stream>>>(Wih, Whh, bih, bhh, h0, Wc, bias, hbuf, flg);

    void* args[] = {(void*)&x, (void*)&c0, (void*)&Wc, (void*)&bias,
                    (void*)&hbuf, (void*)&flg, (void*)&outp};
    hipLaunchCooperativeKernel((void*)lstm_kernel, dim3(NCL*CWG), dim3(512), args, 0, stream);
}

// Round 6
// 217.920 us; speedup vs baseline: 1.6161x; 1.6161x over previous
//
#include <hip/hip_runtime.h>

// LSTM encoder B=1024,S=64,H=256 — v6: tagged self-validating h-exchange.
// 32 clusters x 8 WGs x 512 threads (cooperative, 1 WG/CU). Cluster owns 32
// batches; WG owns 32 h-dims (128 gate rows); each wave holds 16 gate rows of
// W in registers (wf[16], pinned). h exchanged as atomic u64 {tag|2xbf16}:
// publisher fire-and-forget, readers retry stale tags. No drains, no flags,
// no polls; 2 raw lgkmcnt-only barriers per step.

typedef __attribute__((ext_vector_type(8))) short short8;
typedef __attribute__((ext_vector_type(4))) float f32x4;
typedef unsigned long long u64;
typedef unsigned int u32;
typedef unsigned short u16;

#define B_ 1024
#define S_ 64
#define H_ 256
#define G_ 1024
#define KW 512
#define OUTN (B_*S_*H_)
#define APITCH 520      // A-tile pitch (u16)
#define GPITCH 132      // gates tile pitch (f32)
#define NCL 32
#define CWG 8
#define B128 (B_*128)   // u64 slots per parity buffer

__device__ __forceinline__ u16 f2bf(float f){
    u32 u = __builtin_bit_cast(u32, f);
    u = (u + 0x7fffu + ((u >> 16) & 1u)) >> 16;   // RNE
    return (u16)u;
}
__device__ __forceinline__ float sigm(float v){ return 1.0f/(1.0f + __expf(-v)); }
__device__ __forceinline__ float tanh_(float v){ return 2.0f/(1.0f + __expf(-2.0f*v)) - 1.0f; }

// raw workgroup barrier: waits LDS ops only (no vmcnt drain)
__device__ __forceinline__ void wg_barrier_lds(){
    asm volatile("s_waitcnt lgkmcnt(0)" ::: "memory");
    __builtin_amdgcn_sched_barrier(0);
    __builtin_amdgcn_s_barrier();
    __builtin_amdgcn_sched_barrier(0);
}

__global__ __launch_bounds__(256) void prep_kernel(const float* __restrict__ Wih,
        const float* __restrict__ Whh, const float* __restrict__ bih,
        const float* __restrict__ bhh, const float* __restrict__ h0,
        u16* __restrict__ Wc, float* __restrict__ bias, u64* __restrict__ hq){
    int idx = blockIdx.x*256 + threadIdx.x;
    if (idx < G_*KW){
        int g = idx >> 9, k = idx & 511;
        float v = (k < H_) ? Wih[g*H_ + k] : Whh[g*H_ + (k - H_)];
        Wc[idx] = f2bf(v);
    }
    if (idx < G_) bias[idx] = bih[idx] + bhh[idx];
    if (idx < B128){
        int b = idx >> 7, c = idx & 127;
        u32 hp = (u32)f2bf(h0[b*H_ + 2*c]) | ((u32)f2bf(h0[b*H_ + 2*c + 1]) << 16);
        hq[idx] = (u64)hp;                        // h(0), tag = 0
        hq[B128 + idx] = 0xFFFFFFFF00000000ull;   // clear stale tags (prev replay!)
    }
}

__global__ __launch_bounds__(512, 2) void lstm_kernel(
        const float* __restrict__ x, const float* __restrict__ c0,
        const u16* __restrict__ Wc, const float* __restrict__ bias,
        u64* hq, float* __restrict__ out){
    __shared__ u16 At[32*APITCH];    // [batch][k: 0..255=x, 256..511=h]
    __shared__ float Gt[32*GPITCH];  // [batch][128 gate cols]

    const int tid  = threadIdx.x;
    const int lane = tid & 63;
    const int w    = tid >> 6;
    const int wn   = w >> 1, tn = w & 1;
    const int nl   = lane & 15, kg = lane >> 4;
    const int bid  = blockIdx.x;
    const int cl   = bid & (NCL-1);
    const int j    = bid >> 5;        // wg-in-cluster 0..7
    const int b0   = cl * 32;
    const int d0   = j * 32;

    // ---- persistent W: wave holds 16 gate rows ----
    const int grow_idx = wn*256 + d0 + tn*16 + nl;
    short8 wf[16];
    {
        const u16* wp = Wc + (size_t)grow_idx*KW + kg*8;
        #pragma unroll
        for (int kf = 0; kf < 16; ++kf) wf[kf] = *(const short8*)(wp + kf*32);
    }
    #pragma unroll
    for (int kf = 0; kf < 16; ++kf) asm volatile("" : "+v"(wf[kf]));  // pin
    const float bias_l = bias[grow_idx];

    // ---- per-thread roles ----
    const int sb = tid >> 4;          // batch 0..31
    const int dp = tid & 15;          // dim pair / staging col / gather lane
    float c0r, c1r;
    {
        float2 cv = *(const float2*)(c0 + (size_t)(b0+sb)*H_ + d0 + 2*dp);
        c0r = cv.x; c1r = cv.y;
    }

    // remote chunk table: 112 chunks of 2 dims, skipping own [16j,16j+16)
    int rc[7];
    #pragma unroll
    for (int i = 0; i < 7; ++i){
        int m = i*16 + dp;
        rc[i] = m + (m >= 16*j ? 16 : 0);
    }

    // ---- prologue: stage x(0) + h(0); prefetch x(1) ----
    float xr[16];
    {
        const float* xp = x + ((size_t)(b0+sb)*S_ + 0)*H_ + dp*16;
        #pragma unroll
        for (int q = 0; q < 4; ++q){
            f32x4 v = *(const f32x4*)(xp + q*4);
            xr[q*4+0]=v[0]; xr[q*4+1]=v[1]; xr[q*4+2]=v[2]; xr[q*4+3]=v[3];
        }
        u16 tmp[16];
        #pragma unroll
        for (int q = 0; q < 16; ++q) tmp[q] = f2bf(xr[q]);
        *(short8*)(At + sb*APITCH + dp*16)     = *(const short8*)tmp;
        *(short8*)(At + sb*APITCH + dp*16 + 8) = *(const short8*)(tmp+8);
    }
    {
        const u64* hb = hq + (size_t)(b0+sb)*128;
        #pragma unroll
        for (int i = 0; i < 8; ++i){
            int c = dp + 16*i;
            u64 v = hb[c];
            *(u32*)(At + sb*APITCH + H_ + 2*c) = (u32)v;
        }
    }
    {
        const float* xp = x + ((size_t)(b0+sb)*S_ + 1)*H_ + dp*16;
        #pragma unroll
        for (int q = 0; q < 4; ++q){
            f32x4 v = *(const f32x4*)(xp + q*4);
            xr[q*4+0]=v[0]; xr[q*4+1]=v[1]; xr[q*4+2]=v[2]; xr[q*4+3]=v[3];
        }
    }
    __syncthreads();

    u64 gv[7];                        // in-flight gather values (tagged)

    #pragma unroll 1
    for (int s = 0; s < S_; ++s){
        // ---- B: x-part MFMA (frames 0..7) — gather loads fly underneath ----
        f32x4 acc0 = (f32x4){bias_l, bias_l, bias_l, bias_l};
        f32x4 acc1 = acc0;
        const u16* ar = At + nl*APITCH + kg*8;
        #pragma unroll
        for (int kf = 0; kf < 8; ++kf){
            short8 a0 = *(const short8*)(ar + kf*32);
            short8 a1 = *(const short8*)(ar + 16*APITCH + kf*32);
            acc0 = __builtin_amdgcn_mfma_f32_16x16x32_bf16(a0, wf[kf], acc0, 0, 0, 0);
            acc1 = __builtin_amdgcn_mfma_f32_16x16x32_bf16(a1, wf[kf], acc1, 0, 0, 0);
        }

        // ---- C: validate gather tags (retry stale); D: write h(s) -> At ----
        if (s > 0){
            const u64* gb = hq + (size_t)(s & 1)*B128 + (size_t)(b0+sb)*128;
            const u32 want = (u32)s;
            int guard = 0;
            for (;;){
                bool ok = true;
                #pragma unroll
                for (int i = 0; i < 7; ++i)
                    if ((u32)(gv[i] >> 32) != want) ok = false;
                if (__all((int)ok)) break;
                if (++guard > (1<<16)) break;   // fail loud, never hang
                #pragma unroll
                for (int i = 0; i < 7; ++i)
                    if ((u32)(gv[i] >> 32) != want)
                        gv[i] = __hip_atomic_load(gb + rc[i], __ATOMIC_RELAXED,
                                                  __HIP_MEMORY_SCOPE_AGENT);
            }
            #pragma unroll
            for (int i = 0; i < 7; ++i)
                *(u32*)(At + sb*APITCH + H_ + 2*rc[i]) = (u32)gv[i];
        }
        wg_barrier_lds();   // barrier#1: At h-cols complete

        // ---- E: h-part MFMA (frames 8..15) ----
        #pragma unroll
        for (int kf = 8; kf < 16; ++kf){
            short8 a0 = *(const short8*)(ar + kf*32);
            short8 a1 = *(const short8*)(ar + 16*APITCH + kf*32);
            acc0 = __builtin_amdgcn_mfma_f32_16x16x32_bf16(a0, wf[kf], acc0, 0, 0, 0);
            acc1 = __builtin_amdgcn_mfma_f32_16x16x32_bf16(a1, wf[kf], acc1, 0, 0, 0);
        }

        // ---- F: restage x(s+1); Gt stores ----
        if (s + 1 < S_){
            u16 tmp[16];
            #pragma unroll
            for (int q = 0; q < 16; ++q) tmp[q] = f2bf(xr[q]);
            *(short8*)(At + sb*APITCH + dp*16)     = *(const short8*)tmp;
            *(short8*)(At + sb*APITCH + dp*16 + 8) = *(const short8*)(tmp+8);
        }
        {
            const int colc = wn*32 + tn*16 + nl;
            #pragma unroll
            for (int jj = 0; jj < 4; ++jj){
                Gt[(kg*4 + jj)*GPITCH + colc]      = acc0[jj];   // batches 0..15
                Gt[(16 + kg*4 + jj)*GPITCH + colc] = acc1[jj];   // batches 16..31
            }
        }
        wg_barrier_lds();   // barrier#2: Gt + x-restage complete

        // ---- G: cell; publish tagged h; out stores; prefetch; gather issue ----
        {
            const float* gr = Gt + sb*GPITCH + 2*dp;
            float iv0 = gr[0],  iv1 = gr[1];
            float fv0 = gr[32], fv1 = gr[33];
            float gv0 = gr[64], gv1 = gr[65];
            float ov0 = gr[96], ov1 = gr[97];
            float cn0 = sigm(fv0)*c0r + sigm(iv0)*tanh_(gv0);
            float cn1 = sigm(fv1)*c1r + sigm(iv1)*tanh_(gv1);
            float hn0 = sigm(ov0)*tanh_(cn0);
            float hn1 = sigm(ov1)*tanh_(cn1);
            c0r = cn0; c1r = cn1;

            if (s < S_-1){
                u32 hpk = (u32)f2bf(hn0) | ((u32)f2bf(hn1) << 16);
                u64 pv  = ((u64)(u32)(s+1) << 32) | (u64)hpk;
                __hip_atomic_store(hq + (size_t)((s+1)&1)*B128
                                   + (size_t)(b0+sb)*128 + (d0>>1) + dp, pv,
                                   __ATOMIC_RELAXED, __HIP_MEMORY_SCOPE_AGENT);
                *(u32*)(At + sb*APITCH + H_ + d0 + 2*dp) = hpk;  // own slice
            }
            size_t o = ((size_t)(b0+sb)*S_ + s)*H_ + d0 + 2*dp;
            float2 hv; hv.x = hn0; hv.y = hn1;
            *(float2*)(out + o) = hv;
            *(float2*)(out + OUTN + o) = hv;
        }
        if (s + 2 < S_){
            const float* xp = x + ((size_t)(b0+sb)*S_ + (s+2))*H_ + dp*16;
            #pragma unroll
            for (int q = 0; q < 4; ++q){
                f32x4 v = *(const f32x4*)(xp + q*4);
                xr[q*4+0]=v[0]; xr[q*4+1]=v[1]; xr[q*4+2]=v[2]; xr[q*4+3]=v[3];
            }
        }
        if (s + 1 < S_){
            const u64* gb = hq + (size_t)((s+1)&1)*B128 + (size_t)(b0+sb)*128;
            #pragma unroll
            for (int i = 0; i < 7; ++i)
                gv[i] = __hip_atomic_load(gb + rc[i], __ATOMIC_RELAXED,
                                          __HIP_MEMORY_SCOPE_AGENT);
        }
    }
}

extern "C" void kernel_launch(void* const* d_in, const int* in_sizes, int n_in,
                              void* d_out, int out_size, void* d_ws, size_t ws_size,
                              hipStream_t stream){
    const float* x   = (const float*)d_in[0];
    const float* h0  = (const float*)d_in[1];
    const float* c0  = (const float*)d_in[2];
    const float* Wih = (const float*)d_in[3];
    const float* Whh = (const float*)d_in[4];
    const float* bih = (const float*)d_in[5];
    const float* bhh = (const float*)d_in[6];

    u16*   Wc   = (u16*)d_ws;                          // 1 MB @ 0
    float* bias = (float*)((char*)d_ws + 0x100000);    // 4 KB
    u64*   hq   = (u64*)((char*)d_ws + 0x110000);      // 2 MB tagged h (2 parities)
    float* outp = (float*)d_out;

    prep_kernel<<<(G_*KW + 255)/256, 256, 0, stream>>>(Wih, Whh, bih, bhh, h0, Wc, bias, hq);

    void* args[] = {(void*)&x, (void*)&c0, (void*)&Wc, (void*)&bias,
                    (void*)&hq, (void*)&outp};
    hipLaunchCooperativeKernel((void*)lstm_kernel, dim3(NCL*CWG), dim3(512), args, 0, stream);
}